// Round 2
// baseline (101.127 us; speedup 1.0000x reference)
//
#include <hip/hip_runtime.h>

// SparseNeuralNetwork: 256 independent sub-nets j = i*16 + o (i,o in [0,16)).
//   layer0: v[k] = relu(W0[16j+k, i] * x[b,i] + b0[16j+k]),   k in [0,16)
//   layer1: u[m] = relu(b1[8j+m] + sum_k W1[8j+m, 16j+k] * v[k]), m in [0,8)
//   out[b,o] = b2[o] + sum_i sum_m W2[o, 8j+m] * u[m]
//
// R9: same register-resident design as R8 (lane = sub-net j, 176 weights in
// VGPRs, direct gather, single kernel) with three scheduling fixes:
//  1. Per-b 4-step shfl butterfly (64 dependent DS ops/lane) replaced by a
//     single end-of-kernel reduce-scatter (15 shfl + 15 add + 30 cndmask).
//     Pairing (i-bit 0..3) and operand order (own + recv) identical to the
//     old butterfly -> bitwise-identical fp32 sums (absmax 0.0 preserved).
//  2. x loaded as ONE coalesced float4/lane into LDS (1 KB), read per-b as a
//     broadcast ds_read (banks i+16*(b&1), 4-lane same-addr broadcast, no
//     conflicts) -- removes 16 scalar vmem loads issued at t=0.
//  3. 512 blocks x 256 threads (4 og-waves share the x stage and one dispatch
//     packet) instead of 2048 x 64. Same 2048 waves = 2/SIMD exactly.

#define BATCH   8192
#define IN_DIM  16
#define OUT_DIM 16
#define H0      16
#define H1      8
#define D0      (IN_DIM * OUT_DIM * H0)   // 4096
#define D1      (IN_DIM * OUT_DIM * H1)   // 2048
#define NR      176                        // live weights per sub-net

__global__ __launch_bounds__(256, 2) void mlp_fused(
    const float* __restrict__ x,
    const float* __restrict__ W0, const float* __restrict__ b0,
    const float* __restrict__ W1, const float* __restrict__ b1,
    const float* __restrict__ W2, const float* __restrict__ b2,
    float* __restrict__ out)
{
    __shared__ float xs[16 * IN_DIM];       // 16 batch rows x 16 cols = 1 KB

    const int tid = threadIdx.x;            // 0..255
    const int l   = tid & 63;               // lane
    const int og  = tid >> 6;               // o-group = wave id
    const int bb  = blockIdx.x << 4;        // batch base, 16 rows per block
    const int i   = l >> 2;                 // input column
    const int o   = (og << 2) | (l & 3);    // output index
    const int j   = (i << 4) | o;           // sub-net id

    // ---- x stage: wave 0 loads the whole 1 KB chunk, one float4 per lane ----
    if (tid < 64)
        ((float4*)xs)[tid] = ((const float4*)(x + (size_t)bb * IN_DIM))[tid];

    // ---- one-time: gather this lane's 176 weights straight from HBM/L2 ----
    // Layout in w[]: [0..15]=W0 col i, [16..31]=b0, [32..159]=W1 rows,
    // [160..167]=b1, [168..175]=W2 row o slice.  (identical to R7/R8)
    float w[NR];

    #pragma unroll
    for (int k = 0; k < H0; ++k)            // 16 scalar loads (stride 64 B)
        w[k] = W0[(j * H0 + k) * IN_DIM + i];

    {   // b0[j*16 .. j*16+15]: 4 float4
        const float4* __restrict__ p = (const float4*)(b0 + j * H0);
        #pragma unroll
        for (int q = 0; q < 4; ++q) {
            const float4 t = p[q];
            w[16 + 4*q] = t.x; w[17 + 4*q] = t.y; w[18 + 4*q] = t.z; w[19 + 4*q] = t.w;
        }
    }
    #pragma unroll
    for (int m = 0; m < H1; ++m) {          // W1 row (j*8+m), cols j*16..+15: 4 float4
        const float4* __restrict__ p =
            (const float4*)(W1 + (size_t)(j * H1 + m) * D0 + j * H0);
        #pragma unroll
        for (int q = 0; q < 4; ++q) {
            const float4 t = p[q];
            const int base = 32 + m * 16 + 4 * q;
            w[base] = t.x; w[base+1] = t.y; w[base+2] = t.z; w[base+3] = t.w;
        }
    }
    {   // b1[j*8 .. j*8+7]: 2 float4
        const float4* __restrict__ p = (const float4*)(b1 + j * H1);
        #pragma unroll
        for (int q = 0; q < 2; ++q) {
            const float4 t = p[q];
            w[160 + 4*q] = t.x; w[161 + 4*q] = t.y; w[162 + 4*q] = t.z; w[163 + 4*q] = t.w;
        }
    }
    {   // W2[o, j*8 .. j*8+7]: 2 float4
        const float4* __restrict__ p = (const float4*)(W2 + o * D1 + j * H1);
        #pragma unroll
        for (int q = 0; q < 2; ++q) {
            const float4 t = p[q];
            w[168 + 4*q] = t.x; w[169 + 4*q] = t.y; w[170 + 4*q] = t.z; w[171 + 4*q] = t.w;
        }
    }

    const float b2v = b2[o];

    __syncthreads();                        // x stage visible to all 4 waves

    // ---- register-resident compute, 16 batch elems; partials kept per-b ----
    float p_[16];
    #pragma unroll
    for (int b = 0; b < 16; ++b) {
        const float xib = xs[b * IN_DIM + i];   // broadcast ds_read

        float v[H0];
        #pragma unroll
        for (int k = 0; k < H0; ++k)
            v[k] = fmaxf(fmaf(w[k], xib, w[16 + k]), 0.0f);

        float acc = 0.0f;
        #pragma unroll
        for (int m = 0; m < H1; ++m) {
            float u = w[160 + m];
            #pragma unroll
            for (int k = 0; k < H0; ++k)
                u = fmaf(w[32 + m * 16 + k], v[k], u);
            acc = fmaf(w[168 + m], fmaxf(u, 0.0f), acc);
        }
        p_[b] = acc;
    }

    // ---- reduce-scatter over i (lane bits 2..5). Each step s combines
    // lanes differing in i-bit s, keeping the b's whose bit s matches i's.
    // Same pairing order (bit0->bit3) and operand order (own + recv) as the
    // old per-b butterfly -> bitwise-identical sums. Lane ends with b == i.
    float q0[8];
    #pragma unroll
    for (int t = 0; t < 8; ++t) {
        const float keep = (i & 1) ? p_[2*t+1] : p_[2*t];
        const float send = (i & 1) ? p_[2*t]   : p_[2*t+1];
        q0[t] = keep + __shfl_xor(send, 4, 64);
    }
    float q1[4];
    #pragma unroll
    for (int t = 0; t < 4; ++t) {
        const float keep = (i & 2) ? q0[2*t+1] : q0[2*t];
        const float send = (i & 2) ? q0[2*t]   : q0[2*t+1];
        q1[t] = keep + __shfl_xor(send, 8, 64);
    }
    float q2[2];
    #pragma unroll
    for (int t = 0; t < 2; ++t) {
        const float keep = (i & 4) ? q1[2*t+1] : q1[2*t];
        const float send = (i & 4) ? q1[2*t]   : q1[2*t+1];
        q2[t] = keep + __shfl_xor(send, 16, 64);
    }
    const float keep = (i & 8) ? q2[1] : q2[0];
    const float send = (i & 8) ? q2[0] : q2[1];
    const float r = keep + __shfl_xor(send, 32, 64);

    // lane (i,o) now holds out[bb+i][o]; full-wave coalesced-ish store
    out[(size_t)(bb + i) * OUT_DIM + o] = r + b2v;
}

extern "C" void kernel_launch(void* const* d_in, const int* in_sizes, int n_in,
                              void* d_out, int out_size, void* d_ws, size_t ws_size,
                              hipStream_t stream) {
    const float* x  = (const float*)d_in[0];
    const float* W0 = (const float*)d_in[1];
    const float* b0 = (const float*)d_in[2];
    const float* W1 = (const float*)d_in[3];
    const float* b1 = (const float*)d_in[4];
    const float* W2 = (const float*)d_in[5];
    const float* b2 = (const float*)d_in[6];
    float* out = (float*)d_out;
    (void)d_ws; (void)ws_size;              // workspace not used

    // 512 blocks x 4 waves: wave = og, block = 16-row batch chunk
    mlp_fused<<<512, 256, 0, stream>>>(x, W0, b0, W1, b1, W2, b2, out);
}